// Round 1
// baseline (264.574 us; speedup 1.0000x reference)
//
#include <hip/hip_runtime.h>

#define DEVI __device__ __forceinline__

typedef __bf16 v8bf __attribute__((ext_vector_type(8)));
typedef float  v4f  __attribute__((ext_vector_type(4)));

DEVI unsigned short f2bf(float f) {
  unsigned u = __builtin_bit_cast(unsigned, f);
  u += 0x7fffu + ((u >> 16) & 1u);
  return (unsigned short)(u >> 16);
}
DEVI float bf2f(unsigned short u) {
  return __builtin_bit_cast(float, ((unsigned)u) << 16);
}
DEVI v4f MFMA(v8bf a, v8bf b, v4f c) {
  return __builtin_amdgcn_mfma_f32_16x16x32_bf16(a, b, c, 0, 0, 0);
}
DEVI v8bf ldfrag(const unsigned short* p) {
  return __builtin_bit_cast(v8bf, *(const uint4*)p);
}

// ---------------------------------------------------------------------------
// fp32 -> bf16 conversion of X (4,2,1024,512) and Wq/Wk/Wv/Wo (512x512 each)
// into one contiguous bf16 region.  5,242,880 elems, exact grid.
// ---------------------------------------------------------------------------
__global__ __launch_bounds__(256) void convert_kernel(
    const float* __restrict__ X, const float* __restrict__ Wq,
    const float* __restrict__ Wk, const float* __restrict__ Wv,
    const float* __restrict__ Wo, unsigned short* __restrict__ dst)
{
  int t = blockIdx.x * 256 + threadIdx.x;
  int idx = t * 4;
  const float* src;
  if (idx < 4194304) {
    src = X + idx;
  } else {
    int u = idx - 4194304;
    int w = u >> 18;
    const float* W = (w == 0) ? Wq : (w == 1) ? Wk : (w == 2) ? Wv : Wo;
    src = W + (u & 262143);
  }
  float4 f = *(const float4*)src;
  ushort4 o;
  o.x = f2bf(f.x); o.y = f2bf(f.y); o.z = f2bf(f.z); o.w = f2bf(f.w);
  *(ushort4*)&dst[idx] = o;
}

// ---------------------------------------------------------------------------
// C[m][n] = sum_k A[m][k] * W[n][k] + bias[n]     (BT GEMM, M=8192 N=512 K=512)
// 128x128 tile, 256 threads (4 waves, 2x2), bf16 16x16x32 MFMA.
// OUTM=0: bf16 out; OUTM=1: fp32 out. grid.z selects W/bias/C (QKV fusion).
// ---------------------------------------------------------------------------
template<int OUTM>
__global__ __launch_bounds__(256) void gemm_bt(
    const unsigned short* __restrict__ A,
    const unsigned short* __restrict__ W0, const unsigned short* __restrict__ W1,
    const unsigned short* __restrict__ W2,
    const float* __restrict__ b0, const float* __restrict__ b1, const float* __restrict__ b2,
    void* __restrict__ C0, void* __restrict__ C1, void* __restrict__ C2)
{
  const int K = 512, N = 512;
  __shared__ unsigned short sA[128][72];
  __shared__ unsigned short sB[128][72];
  const int z = blockIdx.z;
  const unsigned short* W = (z == 0) ? W0 : (z == 1) ? W1 : W2;
  const float* bias = (z == 0) ? b0 : (z == 1) ? b1 : b2;
  void* C = (z == 0) ? C0 : (z == 1) ? C1 : C2;

  const int tid = threadIdx.x;
  const int lane = tid & 63, wave = tid >> 6;
  const int l15 = lane & 15, quad = lane >> 4;
  const int wm = (wave >> 1) * 64, wn = (wave & 1) * 64;
  const int mbase = blockIdx.y * 128, nbase = blockIdx.x * 128;

  v4f acc[4][4] = {};

  for (int kt = 0; kt < K; kt += 64) {
    __syncthreads();
#pragma unroll
    for (int i = 0; i < 4; i++) {
      int c = tid + 256 * i;
      int row = c >> 3, c8 = (c & 7) * 8;
      *(uint4*)&sA[row][c8] = *(const uint4*)&A[(size_t)(mbase + row) * K + kt + c8];
      *(uint4*)&sB[row][c8] = *(const uint4*)&W[(size_t)(nbase + row) * K + kt + c8];
    }
    __syncthreads();
#pragma unroll
    for (int s = 0; s < 2; s++) {
      v8bf af[4], bf[4];
#pragma unroll
      for (int i = 0; i < 4; i++) af[i] = ldfrag(&sA[wm + i * 16 + l15][s * 32 + quad * 8]);
#pragma unroll
      for (int j = 0; j < 4; j++) bf[j] = ldfrag(&sB[wn + j * 16 + l15][s * 32 + quad * 8]);
#pragma unroll
      for (int i = 0; i < 4; i++)
#pragma unroll
        for (int j = 0; j < 4; j++)
          acc[i][j] = MFMA(af[i], bf[j], acc[i][j]);
    }
  }

#pragma unroll
  for (int i = 0; i < 4; i++)
#pragma unroll
    for (int j = 0; j < 4; j++)
#pragma unroll
      for (int r = 0; r < 4; r++) {
        int row = mbase + wm + i * 16 + quad * 4 + r;
        int col = nbase + wn + j * 16 + l15;
        float v = acc[i][j][r] + bias[col];
        if (OUTM == 0) ((unsigned short*)C)[(size_t)row * N + col] = f2bf(v);
        else           ((float*)C)[(size_t)row * N + col] = v;
      }
}

// ---------------------------------------------------------------------------
// V (rows=(bs*1024+t), col=h*64+hd) -> VT[((bs*8+h)*64+hd)*1024 + t]
// 64x64 LDS tile per (t-tile, h, bs).
// ---------------------------------------------------------------------------
__global__ __launch_bounds__(256) void transpose_v(
    const unsigned short* __restrict__ V, unsigned short* __restrict__ VT)
{
  __shared__ unsigned short sT[64][72];
  const int tid = threadIdx.x;
  const int tt = blockIdx.x, h = blockIdx.y, bs = blockIdx.z;
#pragma unroll
  for (int i = 0; i < 2; i++) {
    int c = tid + 256 * i;
    int t_ = c >> 3, c8 = (c & 7) * 8;
    *(uint4*)&sT[t_][c8] = *(const uint4*)&V[(size_t)(bs * 1024 + tt * 64 + t_) * 512 + h * 64 + c8];
  }
  __syncthreads();
#pragma unroll
  for (int i = 0; i < 2; i++) {
    int c = tid + 256 * i;
    int hd = c >> 3, t8 = (c & 7) * 8;
    unsigned short tmp[8];
#pragma unroll
    for (int j = 0; j < 8; j++) tmp[j] = sT[t8 + j][hd];
    uint4 o;
    o.x = (unsigned)tmp[0] | ((unsigned)tmp[1] << 16);
    o.y = (unsigned)tmp[2] | ((unsigned)tmp[3] << 16);
    o.z = (unsigned)tmp[4] | ((unsigned)tmp[5] << 16);
    o.w = (unsigned)tmp[6] | ((unsigned)tmp[7] << 16);
    *(uint4*)&VT[(size_t)((bs * 8 + h) * 64 + hd) * 1024 + tt * 64 + t8] = o;
  }
}

// ---------------------------------------------------------------------------
// Fused competitive cross-attention.
// Block = (b, h, 64-row q-tile), 4 waves: wave>>1 = direction (0: Q1K2/V2 ->
// stream0 out, 1: Q2K1/V1 -> stream1 out), wave&1 = 32-row half.
// Pass 1: streaming softmax stats (m,l) per row.  Pass 2: recompute logits,
// probs -> LDS (bf16), competitive combine, PV MFMA from V^T tiles.
// ---------------------------------------------------------------------------
__global__ __launch_bounds__(256) void attn_kernel(
    const unsigned short* __restrict__ Qg, const unsigned short* __restrict__ Kg,
    const unsigned short* __restrict__ VTg, unsigned short* __restrict__ Hc)
{
  __shared__ unsigned short sK[2][64][72];
  __shared__ unsigned short sV[2][64][72];
  __shared__ unsigned short sS[2][64][72];

  const int tid = threadIdx.x;
  const int lane = tid & 63, wave = tid >> 6;
  const int l15 = lane & 15, quad = lane >> 4;
  const int dir = wave >> 1, mh = wave & 1;
  const int qt = blockIdx.x, h = blockIdx.y, b = blockIdx.z;
  const float scale = 0.125f;   // 1/sqrt(64)
  const int qs = dir, ks = 1 - dir;

  // Q fragments held in registers for the whole kernel (16B/lane contiguous)
  v8bf qf[2][2];
#pragma unroll
  for (int i = 0; i < 2; i++)
#pragma unroll
    for (int s = 0; s < 2; s++) {
      int row = (b * 2 + qs) * 1024 + qt * 64 + mh * 32 + i * 16 + l15;
      qf[i][s] = ldfrag(&Qg[(size_t)row * 512 + h * 64 + s * 32 + quad * 8]);
    }

  float mrun[2][4], lrun[2][4];
#pragma unroll
  for (int i = 0; i < 2; i++)
#pragma unroll
    for (int r = 0; r < 4; r++) { mrun[i][r] = -3e38f; lrun[i][r] = 0.f; }

  // ---- pass 1: softmax stats ----
  for (int kt = 0; kt < 16; kt++) {
    __syncthreads();
#pragma unroll
    for (int i = 0; i < 4; i++) {
      int c = tid + 256 * i;
      int st = c >> 9, row = (c >> 3) & 63, c8 = (c & 7) * 8;
      int grow = (b * 2 + st) * 1024 + kt * 64 + row;
      *(uint4*)&sK[st][row][c8] = *(const uint4*)&Kg[(size_t)grow * 512 + h * 64 + c8];
    }
    __syncthreads();
    v4f acc[2][4] = {};
#pragma unroll
    for (int s = 0; s < 2; s++) {
      v8bf kf[4];
#pragma unroll
      for (int j = 0; j < 4; j++) kf[j] = ldfrag(&sK[ks][j * 16 + l15][s * 32 + quad * 8]);
#pragma unroll
      for (int i = 0; i < 2; i++)
#pragma unroll
        for (int j = 0; j < 4; j++)
          acc[i][j] = MFMA(qf[i][s], kf[j], acc[i][j]);
    }
#pragma unroll
    for (int i = 0; i < 2; i++)
#pragma unroll
      for (int r = 0; r < 4; r++) {
        float v = fmaxf(fmaxf(acc[i][0][r], acc[i][1][r]), fmaxf(acc[i][2][r], acc[i][3][r]));
        v = fmaxf(v, __shfl_xor(v, 1));
        v = fmaxf(v, __shfl_xor(v, 2));
        v = fmaxf(v, __shfl_xor(v, 4));
        v = fmaxf(v, __shfl_xor(v, 8));
        float mnew = fmaxf(mrun[i][r], v * scale);
        float p = __expf(fmaf(acc[i][0][r], scale, -mnew)) + __expf(fmaf(acc[i][1][r], scale, -mnew))
                + __expf(fmaf(acc[i][2][r], scale, -mnew)) + __expf(fmaf(acc[i][3][r], scale, -mnew));
        p += __shfl_xor(p, 1);
        p += __shfl_xor(p, 2);
        p += __shfl_xor(p, 4);
        p += __shfl_xor(p, 8);
        lrun[i][r] = lrun[i][r] * __expf(mrun[i][r] - mnew) + p;
        mrun[i][r] = mnew;
      }
  }

  float linv[2][4];
#pragma unroll
  for (int i = 0; i < 2; i++)
#pragma unroll
    for (int r = 0; r < 4; r++) linv[i][r] = 1.f / lrun[i][r];

  v4f oacc[2][4] = {};

  // ---- pass 2: recompute logits, combine, PV ----
  for (int kt = 0; kt < 16; kt++) {
    __syncthreads();
#pragma unroll
    for (int i = 0; i < 4; i++) {
      int c = tid + 256 * i;
      int st = c >> 9, row = (c >> 3) & 63, c8 = (c & 7) * 8;
      int grow = (b * 2 + st) * 1024 + kt * 64 + row;
      *(uint4*)&sK[st][row][c8] = *(const uint4*)&Kg[(size_t)grow * 512 + h * 64 + c8];
      int vrow = ((b * 2 + st) * 8 + h) * 64 + row;   // row acts as hd here
      *(uint4*)&sV[st][row][c8] = *(const uint4*)&VTg[(size_t)vrow * 1024 + kt * 64 + c8];
    }
    __syncthreads();
    v4f acc[2][4] = {};
#pragma unroll
    for (int s = 0; s < 2; s++) {
      v8bf kf[4];
#pragma unroll
      for (int j = 0; j < 4; j++) kf[j] = ldfrag(&sK[ks][j * 16 + l15][s * 32 + quad * 8]);
#pragma unroll
      for (int i = 0; i < 2; i++)
#pragma unroll
        for (int j = 0; j < 4; j++)
          acc[i][j] = MFMA(qf[i][s], kf[j], acc[i][j]);
    }
    // probabilities -> LDS (bf16) for cross-wave exchange
#pragma unroll
    for (int i = 0; i < 2; i++)
#pragma unroll
      for (int j = 0; j < 4; j++)
#pragma unroll
        for (int r = 0; r < 4; r++) {
          float p = __expf(fmaf(acc[i][j][r], scale, -mrun[i][r])) * linv[i][r];
          sS[dir][mh * 32 + i * 16 + quad * 4 + r][j * 16 + l15] = f2bf(p);
        }
    __syncthreads();
#pragma unroll
    for (int s = 0; s < 2; s++) {
      v8bf afr[2];
#pragma unroll
      for (int i = 0; i < 2; i++) {
        int row = mh * 32 + i * 16 + l15;
        uint4 uo = *(const uint4*)&sS[dir][row][s * 32 + quad * 8];
        uint4 ut = *(const uint4*)&sS[1 - dir][row][s * 32 + quad * 8];
        const unsigned short* ow = (const unsigned short*)&uo;
        const unsigned short* tw = (const unsigned short*)&ut;
        v8bf a;
#pragma unroll
        for (int j = 0; j < 8; j++) {
          float fo = bf2f(ow[j]), ft = bf2f(tw[j]);
          float r2 = fo * __builtin_amdgcn_rcpf(fo + ft + 1e-6f);
          a[j] = __builtin_bit_cast(__bf16, f2bf(r2));
        }
        afr[i] = a;
      }
      v8bf vf[4];
#pragma unroll
      for (int j = 0; j < 4; j++) vf[j] = ldfrag(&sV[ks][j * 16 + l15][s * 32 + quad * 8]);
#pragma unroll
      for (int i = 0; i < 2; i++)
#pragma unroll
        for (int j = 0; j < 4; j++)
          oacc[i][j] = MFMA(afr[i], vf[j], oacc[i][j]);
    }
  }

#pragma unroll
  for (int i = 0; i < 2; i++)
#pragma unroll
    for (int j = 0; j < 4; j++)
#pragma unroll
      for (int r = 0; r < 4; r++) {
        int row = (b * 2 + dir) * 1024 + qt * 64 + mh * 32 + i * 16 + quad * 4 + r;
        int col = h * 64 + j * 16 + l15;
        Hc[(size_t)row * 512 + col] = f2bf(oacc[i][j][r]);
      }
}

// ---------------------------------------------------------------------------
// LayerNorm (over D=512) + gate + residual.  One block per row.
// ---------------------------------------------------------------------------
__global__ __launch_bounds__(256) void ln_kernel(
    const float* __restrict__ P, const float* __restrict__ hidden,
    const float* __restrict__ ln_g, const float* __restrict__ ln_b,
    const float* __restrict__ gate, float* __restrict__ out)
{
  const int row = blockIdx.x;
  const int s = (row >> 10) & 1;
  const int tid = threadIdx.x;
  const int d0 = tid * 2;
  float2 x = *(const float2*)&P[(size_t)row * 512 + d0];
  float s1 = x.x + x.y;
  float s2 = x.x * x.x + x.y * x.y;
#pragma unroll
  for (int m = 1; m < 64; m <<= 1) { s1 += __shfl_xor(s1, m); s2 += __shfl_xor(s2, m); }
  __shared__ float r1[4], r2[4];
  if ((tid & 63) == 0) { r1[tid >> 6] = s1; r2[tid >> 6] = s2; }
  __syncthreads();
  s1 = r1[0] + r1[1] + r1[2] + r1[3];
  s2 = r2[0] + r2[1] + r2[2] + r2[3];
  float mu = s1 * (1.f / 512.f);
  float var = s2 * (1.f / 512.f) - mu * mu;
  float rs = rsqrtf(var + 1e-5f);
  float al = gate[s];
  float2 hv = *(const float2*)&hidden[(size_t)row * 512 + d0];
  float2 o;
  o.x = hv.x + ((x.x - mu) * rs * ln_g[s * 512 + d0]     + ln_b[s * 512 + d0])     * al;
  o.y = hv.y + ((x.y - mu) * rs * ln_g[s * 512 + d0 + 1] + ln_b[s * 512 + d0 + 1]) * al;
  *(float2*)&out[(size_t)row * 512 + d0] = o;
}

// ---------------------------------------------------------------------------
extern "C" void kernel_launch(void* const* d_in, const int* in_sizes, int n_in,
                              void* d_out, int out_size, void* d_ws, size_t ws_size,
                              hipStream_t stream)
{
  const float* hidden = (const float*)d_in[0];
  const float* Wq = (const float*)d_in[1];
  const float* bq = (const float*)d_in[2];
  const float* Wk = (const float*)d_in[3];
  const float* bk = (const float*)d_in[4];
  const float* Wv = (const float*)d_in[5];
  const float* bv = (const float*)d_in[6];
  const float* Wo = (const float*)d_in[7];
  const float* bo = (const float*)d_in[8];
  const float* ln_g = (const float*)d_in[9];
  const float* ln_b = (const float*)d_in[10];
  const float* gate = (const float*)d_in[11];

  // workspace layout (bf16 elems): X, Wq, Wk, Wv, Wo, Q, K, V, VT, Hcat, then fp32 P
  unsigned short* U = (unsigned short*)d_ws;
  unsigned short* Xbf = U;
  unsigned short* Wqb = U + 4194304;
  unsigned short* Wkb = U + 4456448;
  unsigned short* Wvb = U + 4718592;
  unsigned short* Wob = U + 4980736;
  unsigned short* Qg  = U + 5242880;
  unsigned short* Kg  = U + 9437184;
  unsigned short* Vg  = U + 13631488;
  unsigned short* VT  = U + 17825792;
  unsigned short* Hc  = U + 22020096;
  float* P = (float*)((char*)d_ws + 52428800);

  convert_kernel<<<dim3(5120), 256, 0, stream>>>(hidden, Wq, Wk, Wv, Wo, Xbf);
  gemm_bt<0><<<dim3(4, 64, 3), 256, 0, stream>>>(Xbf, Wqb, Wkb, Wvb, bq, bk, bv, Qg, Kg, Vg);
  transpose_v<<<dim3(16, 8, 8), 256, 0, stream>>>(Vg, VT);
  attn_kernel<<<dim3(16, 8, 4), 256, 0, stream>>>(Qg, Kg, VT, Hc);
  gemm_bt<1><<<dim3(4, 64, 1), 256, 0, stream>>>(Hc, Wob, Wob, Wob, bo, bo, bo, P, P, P);
  ln_kernel<<<dim3(8192), 256, 0, stream>>>(P, hidden, ln_g, ln_b, gate, (float*)d_out);
}